// Round 1
// baseline (860.458 us; speedup 1.0000x reference)
//
#include <hip/hip_runtime.h>
#include <cstdint>
#include <cstddef>

// Problem constants
#define MM 8192      // batch
#define KK 4096      // in_dim
#define NN 2048      // out_dim
#define DEPTH_N 9

typedef __attribute__((ext_vector_type(8))) short bf16x8;    // 8 bf16 = 4 VGPRs
typedef __attribute__((ext_vector_type(16))) float f32x16;   // MFMA 32x32 accumulator

static_assert(sizeof(bf16x8) == 16, "bf16x8 must be 16B");
static_assert(sizeof(f32x16) == 64, "f32x16 must be 64B");

typedef const __attribute__((address_space(1))) uint32_t* gptr_t;
typedef __attribute__((address_space(3))) uint32_t* lptr_t;

__device__ __forceinline__ void load_lds16(const void* g, void* l) {
  // async global->LDS, 16B per lane; LDS dest is wave-uniform base + lane*16
  __builtin_amdgcn_global_load_lds((gptr_t)g, (lptr_t)l, 16, 0, 0);
}

union FragU {
  uint32_t u[4];
  bf16x8 v;
};

// Split a float4 into packed bf16 hi (truncate) and bf16 lo (truncate of residual).
// hi+lo represents x to ~2^-16 relative; residual x-hi is exact in fp32.
__device__ __forceinline__ void split4(float4 v, uint32_t& h01, uint32_t& h23,
                                       uint32_t& l01, uint32_t& l23) {
  uint32_t ux = __float_as_uint(v.x), uy = __float_as_uint(v.y);
  uint32_t uz = __float_as_uint(v.z), uw = __float_as_uint(v.w);
  // D = src1.hi16 | src0.hi16<<16  (element order: low half first)
  h01 = __builtin_amdgcn_perm(uy, ux, 0x07060302u);
  h23 = __builtin_amdgcn_perm(uw, uz, 0x07060302u);
  float rx = v.x - __uint_as_float(ux & 0xFFFF0000u);
  float ry = v.y - __uint_as_float(uy & 0xFFFF0000u);
  float rz = v.z - __uint_as_float(uz & 0xFFFF0000u);
  float rw = v.w - __uint_as_float(uw & 0xFFFF0000u);
  l01 = __builtin_amdgcn_perm(__float_as_uint(ry), __float_as_uint(rx), 0x07060302u);
  l23 = __builtin_amdgcn_perm(__float_as_uint(rw), __float_as_uint(rz), 0x07060302u);
}

// ---------------------------------------------------------------------------
// Kernel 1: transpose + bf16-split classical_weights (K x N fp32, row-major)
// into BtHi/BtLo (N x K bf16, row-major).
// ---------------------------------------------------------------------------
__global__ __launch_bounds__(256) void prep_bt_kernel(
    const float* __restrict__ W,
    uint16_t* __restrict__ btHi,
    uint16_t* __restrict__ btLo) {
  __shared__ float tile[64][65];  // +1 pad breaks transpose-read conflicts
  const int k0 = blockIdx.x * 64;
  const int n0 = blockIdx.y * 64;
  const int c4 = (threadIdx.x & 15) * 4;
  const int r16 = threadIdx.x >> 4;  // 0..15
#pragma unroll
  for (int p = 0; p < 4; ++p) {
    int r = p * 16 + r16;
    float4 v = *(const float4*)(W + (size_t)(k0 + r) * NN + n0 + c4);
    tile[r][c4 + 0] = v.x;
    tile[r][c4 + 1] = v.y;
    tile[r][c4 + 2] = v.z;
    tile[r][c4 + 3] = v.w;
  }
  __syncthreads();
#pragma unroll
  for (int p = 0; p < 4; ++p) {
    int n = p * 16 + r16;
    ushort4 h, l;
    float f0 = tile[c4 + 0][n];
    float f1 = tile[c4 + 1][n];
    float f2 = tile[c4 + 2][n];
    float f3 = tile[c4 + 3][n];
    uint32_t u0 = __float_as_uint(f0), u1 = __float_as_uint(f1);
    uint32_t u2 = __float_as_uint(f2), u3 = __float_as_uint(f3);
    h.x = (uint16_t)(u0 >> 16);
    h.y = (uint16_t)(u1 >> 16);
    h.z = (uint16_t)(u2 >> 16);
    h.w = (uint16_t)(u3 >> 16);
    float r0 = f0 - __uint_as_float(u0 & 0xFFFF0000u);
    float r1 = f1 - __uint_as_float(u1 & 0xFFFF0000u);
    float r2 = f2 - __uint_as_float(u2 & 0xFFFF0000u);
    float r3 = f3 - __uint_as_float(u3 & 0xFFFF0000u);
    l.x = (uint16_t)(__float_as_uint(r0) >> 16);
    l.y = (uint16_t)(__float_as_uint(r1) >> 16);
    l.z = (uint16_t)(__float_as_uint(r2) >> 16);
    l.w = (uint16_t)(__float_as_uint(r3) >> 16);
    size_t off = (size_t)(n0 + n) * KK + k0 + c4;
    *(ushort4*)(btHi + off) = h;
    *(ushort4*)(btLo + off) = l;
  }
}

// ---------------------------------------------------------------------------
// Kernel 2: bias2[j] = classical_biases[j] + (1/K) * prod_{d,c} cos^2(uw[d,j,c])
// (the scan on a constant state collapses to a cosine product)
// ---------------------------------------------------------------------------
__global__ __launch_bounds__(256) void prep_bias_kernel(
    const float* __restrict__ uw,
    const float* __restrict__ cb,
    float* __restrict__ bias2) {
  int j = blockIdx.x * 256 + threadIdx.x;  // grid covers exactly NN
  float p = 1.0f / (float)KK;
#pragma unroll
  for (int d = 0; d < DEPTH_N; ++d) {
    // uw[d, j, c] flat = d*KK*NN + j*NN + c ; 16B aligned
    float4 v = *(const float4*)(uw + (size_t)d * KK * NN + (size_t)j * NN);
    float c0 = cosf(v.x), c1 = cosf(v.y), c2 = cosf(v.z);
    p *= (c0 * c0) * (c1 * c1) * (c2 * c2);
  }
  bias2[j] = cb[j] + p;
}

// ---------------------------------------------------------------------------
// Kernel 3: split-bf16 GEMM  out = tanh(x @ W + bias2)
//   block tile 128x128, BK=32, 4 waves each 64x64 via 2x2 mfma_f32_32x32x16_bf16
//   A staged fp32 via global_load_lds (split in-register after ds_read_b128)
//   B staged as pre-split bf16 hi/lo via global_load_lds
//   LDS 16B-blocks XOR-swizzled so ds_read_b128 is bank-conflict-free
// ---------------------------------------------------------------------------
__global__ __launch_bounds__(256, 2) void unl_gemm_kernel(
    const float* __restrict__ X,
    const uint16_t* __restrict__ BtHi,
    const uint16_t* __restrict__ BtLo,
    const float* __restrict__ bias2,
    float* __restrict__ Out) {
  __shared__ __align__(16) uint8_t smem[32768];
  float* sA = (float*)smem;                   // [128][32] fp32, swizzled (16KB)
  uint16_t* sBh = (uint16_t*)(smem + 16384);  // [128][32] bf16 hi (8KB)
  uint16_t* sBl = (uint16_t*)(smem + 24576);  // [128][32] bf16 lo (8KB)

  const int tid = threadIdx.x;
  const int lane = tid & 63;
  const int wave = tid >> 6;
  const int wM = wave >> 1;
  const int wN = wave & 1;
  const int lane31 = lane & 31;
  const int kh = lane >> 5;  // k-half selector for MFMA operand layout

  const int bidx = blockIdx.x;
  const int m0 = (bidx & 63) * 128;  // 64 m-tiles
  const int n0 = (bidx >> 6) * 128;  // 16 n-tiles

  // ---- staging descriptors (A: 16 x 1KB chunks; B: 8 x 1KB each) ----
  const float* aG[4];
  float* aLds[4];
#pragma unroll
  for (int q = 0; q < 4; ++q) {
    int idx = wave * 4 + q;            // 0..15
    int row = idx * 8 + (lane >> 3);   // 8 rows per chunk, 128B/row
    int p = lane & 7;                  // physical 16B block within row
    int c = p ^ (row & 7);             // logical k-block fetched into it
    aG[q] = X + (size_t)(m0 + row) * KK + c * 4;
    aLds[q] = sA + idx * 256;          // wave-uniform LDS base
  }
  const uint16_t* bGh[2];
  const uint16_t* bGl[2];
  uint16_t* bLdsH[2];
  uint16_t* bLdsL[2];
#pragma unroll
  for (int q = 0; q < 2; ++q) {
    int idx = wave * 2 + q;            // 0..7
    int row = idx * 16 + (lane >> 2);  // 16 rows per chunk, 64B/row
    int p = lane & 3;
    int c = p ^ ((row >> 1) & 3);
    bGh[q] = BtHi + (size_t)(n0 + row) * KK + c * 8;
    bGl[q] = BtLo + (size_t)(n0 + row) * KK + c * 8;
    bLdsH[q] = sBh + idx * 512;
    bLdsL[q] = sBl + idx * 512;
  }

  // ---- fragment read offsets (swizzle-corrected) ----
  int aOff[2][2][2];  // [mt][s][half16B], float index
#pragma unroll
  for (int mt = 0; mt < 2; ++mt) {
    int row = wM * 64 + mt * 32 + lane31;
#pragma unroll
    for (int s = 0; s < 2; ++s) {
#pragma unroll
      for (int h2 = 0; h2 < 2; ++h2) {
        int c = 4 * s + 2 * kh + h2;  // logical 16B block (4 floats)
        aOff[mt][s][h2] = row * 32 + (c ^ (row & 7)) * 4;
      }
    }
  }
  int bOff[2][2];  // [nt][s], uint16 index
#pragma unroll
  for (int nt = 0; nt < 2; ++nt) {
    int row = wN * 64 + nt * 32 + lane31;
#pragma unroll
    for (int s = 0; s < 2; ++s) {
      int c = 2 * s + kh;  // logical 16B block (8 bf16)
      bOff[nt][s] = row * 32 + (c ^ ((row >> 1) & 3)) * 8;
    }
  }

  f32x16 acc[2][2];
#pragma unroll
  for (int mt = 0; mt < 2; ++mt)
#pragma unroll
    for (int nt = 0; nt < 2; ++nt)
#pragma unroll
      for (int r = 0; r < 16; ++r) acc[mt][nt][r] = 0.0f;

  for (int kt = 0; kt < KK; kt += 32) {
    __syncthreads();  // previous tile fully consumed
#pragma unroll
    for (int q = 0; q < 4; ++q) load_lds16(aG[q] + kt, aLds[q]);
#pragma unroll
    for (int q = 0; q < 2; ++q) {
      load_lds16(bGh[q] + kt, bLdsH[q]);
      load_lds16(bGl[q] + kt, bLdsL[q]);
    }
    __syncthreads();  // drains vmcnt: staging complete

#pragma unroll
    for (int s = 0; s < 2; ++s) {
      bf16x8 ah[2], al[2], bh[2], bl[2];
#pragma unroll
      for (int mt = 0; mt < 2; ++mt) {
        float4 v0 = *(const float4*)(sA + aOff[mt][s][0]);
        float4 v1 = *(const float4*)(sA + aOff[mt][s][1]);
        FragU uh, ul;
        split4(v0, uh.u[0], uh.u[1], ul.u[0], ul.u[1]);
        split4(v1, uh.u[2], uh.u[3], ul.u[2], ul.u[3]);
        ah[mt] = uh.v;
        al[mt] = ul.v;
      }
#pragma unroll
      for (int nt = 0; nt < 2; ++nt) {
        bh[nt] = *(const bf16x8*)(sBh + bOff[nt][s]);
        bl[nt] = *(const bf16x8*)(sBl + bOff[nt][s]);
      }
#pragma unroll
      for (int mt = 0; mt < 2; ++mt) {
#pragma unroll
        for (int nt = 0; nt < 2; ++nt) {
          acc[mt][nt] = __builtin_amdgcn_mfma_f32_32x32x16_bf16(ah[mt], bh[nt], acc[mt][nt], 0, 0, 0);
          acc[mt][nt] = __builtin_amdgcn_mfma_f32_32x32x16_bf16(ah[mt], bl[nt], acc[mt][nt], 0, 0, 0);
          acc[mt][nt] = __builtin_amdgcn_mfma_f32_32x32x16_bf16(al[mt], bh[nt], acc[mt][nt], 0, 0, 0);
        }
      }
    }
  }

  // ---- epilogue: out = tanh(acc + bias2) ----
  // C/D layout (verified m74/m101): col = lane&31, row = (r&3) + 8*(r>>2) + 4*kh
#pragma unroll
  for (int nt = 0; nt < 2; ++nt) {
    int col = n0 + wN * 64 + nt * 32 + lane31;
    float b2 = bias2[col];
#pragma unroll
    for (int mt = 0; mt < 2; ++mt) {
#pragma unroll
      for (int r = 0; r < 16; ++r) {
        int rowl = (r & 3) + 8 * (r >> 2) + 4 * kh;
        int grow = m0 + wM * 64 + mt * 32 + rowl;
        float z = acc[mt][nt][r] + b2;
        z = fminf(fmaxf(z, -12.0f), 12.0f);  // tanh saturated well before 12
        float t = __expf(2.0f * z);
        Out[(size_t)grow * NN + col] = (t - 1.0f) / (t + 1.0f);
      }
    }
  }
}

// ---------------------------------------------------------------------------
extern "C" void kernel_launch(void* const* d_in, const int* in_sizes, int n_in,
                              void* d_out, int out_size, void* d_ws, size_t ws_size,
                              hipStream_t stream) {
  const float* x = (const float*)d_in[0];   // (8192, 4096)
  const float* uw = (const float*)d_in[1];  // (9, 4096, 2048)
  const float* cw = (const float*)d_in[2];  // (4096, 2048)
  const float* cb = (const float*)d_in[3];  // (2048,)
  float* out = (float*)d_out;               // (8192, 2048)

  // workspace layout: BtHi (16MB) | BtLo (16MB) | bias2 (8KB)
  uint16_t* btHi = (uint16_t*)d_ws;
  uint16_t* btLo = btHi + (size_t)NN * KK;
  float* bias2 = (float*)(btLo + (size_t)NN * KK);

  prep_bt_kernel<<<dim3(KK / 64, NN / 64), 256, 0, stream>>>(cw, btHi, btLo);
  prep_bias_kernel<<<dim3(NN / 256), 256, 0, stream>>>(uw, cb, bias2);
  unl_gemm_kernel<<<dim3((MM / 128) * (NN / 128)), 256, 0, stream>>>(x, btHi, btLo, bias2, out);
}

// Round 2
// 814.036 us; speedup vs baseline: 1.0570x; 1.0570x over previous
//
#include <hip/hip_runtime.h>
#include <cstdint>
#include <cstddef>

// Problem constants
#define MM 8192      // batch
#define KK 4096      // in_dim
#define NN 2048      // out_dim
#define DEPTH_N 9

typedef __attribute__((ext_vector_type(8))) short bf16x8;    // 8 bf16 = 4 VGPRs
typedef __attribute__((ext_vector_type(16))) float f32x16;   // MFMA 32x32 accumulator

static_assert(sizeof(bf16x8) == 16, "bf16x8 must be 16B");
static_assert(sizeof(f32x16) == 64, "f32x16 must be 64B");

typedef const __attribute__((address_space(1))) uint32_t* gptr_t;
typedef __attribute__((address_space(3))) uint32_t* lptr_t;

__device__ __forceinline__ void load_lds16(const void* g, void* l) {
  // async global->LDS, 16B per lane; LDS dest is wave-uniform base + lane*16
  __builtin_amdgcn_global_load_lds((gptr_t)g, (lptr_t)l, 16, 0, 0);
}

union FragU {
  uint32_t u[4];
  bf16x8 v;
};

// Split a float4 into packed bf16 hi (truncate) and bf16 lo (truncate of residual).
__device__ __forceinline__ void split4(float4 v, uint32_t& h01, uint32_t& h23,
                                       uint32_t& l01, uint32_t& l23) {
  uint32_t ux = __float_as_uint(v.x), uy = __float_as_uint(v.y);
  uint32_t uz = __float_as_uint(v.z), uw = __float_as_uint(v.w);
  // D = src1.hi16 | src0.hi16<<16  (element order: low half first)
  h01 = __builtin_amdgcn_perm(uy, ux, 0x07060302u);
  h23 = __builtin_amdgcn_perm(uw, uz, 0x07060302u);
  float rx = v.x - __uint_as_float(ux & 0xFFFF0000u);
  float ry = v.y - __uint_as_float(uy & 0xFFFF0000u);
  float rz = v.z - __uint_as_float(uz & 0xFFFF0000u);
  float rw = v.w - __uint_as_float(uw & 0xFFFF0000u);
  l01 = __builtin_amdgcn_perm(__float_as_uint(ry), __float_as_uint(rx), 0x07060302u);
  l23 = __builtin_amdgcn_perm(__float_as_uint(rw), __float_as_uint(rz), 0x07060302u);
}

// ---------------------------------------------------------------------------
// Kernel 1: transpose + bf16-split classical_weights (K x N fp32, row-major)
// into BtHi/BtLo (N x K bf16, row-major).
// ---------------------------------------------------------------------------
__global__ __launch_bounds__(256) void prep_bt_kernel(
    const float* __restrict__ W,
    uint16_t* __restrict__ btHi,
    uint16_t* __restrict__ btLo) {
  __shared__ float tile[64][65];  // +1 pad breaks transpose-read conflicts
  const int k0 = blockIdx.x * 64;
  const int n0 = blockIdx.y * 64;
  const int c4 = (threadIdx.x & 15) * 4;
  const int r16 = threadIdx.x >> 4;  // 0..15
#pragma unroll
  for (int p = 0; p < 4; ++p) {
    int r = p * 16 + r16;
    float4 v = *(const float4*)(W + (size_t)(k0 + r) * NN + n0 + c4);
    tile[r][c4 + 0] = v.x;
    tile[r][c4 + 1] = v.y;
    tile[r][c4 + 2] = v.z;
    tile[r][c4 + 3] = v.w;
  }
  __syncthreads();
#pragma unroll
  for (int p = 0; p < 4; ++p) {
    int n = p * 16 + r16;
    ushort4 h, l;
    float f0 = tile[c4 + 0][n];
    float f1 = tile[c4 + 1][n];
    float f2 = tile[c4 + 2][n];
    float f3 = tile[c4 + 3][n];
    uint32_t u0 = __float_as_uint(f0), u1 = __float_as_uint(f1);
    uint32_t u2 = __float_as_uint(f2), u3 = __float_as_uint(f3);
    h.x = (uint16_t)(u0 >> 16);
    h.y = (uint16_t)(u1 >> 16);
    h.z = (uint16_t)(u2 >> 16);
    h.w = (uint16_t)(u3 >> 16);
    float r0 = f0 - __uint_as_float(u0 & 0xFFFF0000u);
    float r1 = f1 - __uint_as_float(u1 & 0xFFFF0000u);
    float r2 = f2 - __uint_as_float(u2 & 0xFFFF0000u);
    float r3 = f3 - __uint_as_float(u3 & 0xFFFF0000u);
    l.x = (uint16_t)(__float_as_uint(r0) >> 16);
    l.y = (uint16_t)(__float_as_uint(r1) >> 16);
    l.z = (uint16_t)(__float_as_uint(r2) >> 16);
    l.w = (uint16_t)(__float_as_uint(r3) >> 16);
    size_t off = (size_t)(n0 + n) * KK + k0 + c4;
    *(ushort4*)(btHi + off) = h;
    *(ushort4*)(btLo + off) = l;
  }
}

// ---------------------------------------------------------------------------
// Kernel 2: bias2[j] = classical_biases[j] + (1/K) * prod_{d,c} cos^2(uw[d,j,c])
// (the scan on a constant state collapses to a cosine product)
// ---------------------------------------------------------------------------
__global__ __launch_bounds__(256) void prep_bias_kernel(
    const float* __restrict__ uw,
    const float* __restrict__ cb,
    float* __restrict__ bias2) {
  int j = blockIdx.x * 256 + threadIdx.x;  // grid covers exactly NN
  float p = 1.0f / (float)KK;
#pragma unroll
  for (int d = 0; d < DEPTH_N; ++d) {
    float4 v = *(const float4*)(uw + (size_t)d * KK * NN + (size_t)j * NN);
    float c0 = cosf(v.x), c1 = cosf(v.y), c2 = cosf(v.z);
    p *= (c0 * c0) * (c1 * c1) * (c2 * c2);
  }
  bias2[j] = cb[j] + p;
}

// ---------------------------------------------------------------------------
// Kernel 3: split-bf16 GEMM  out = tanh(x @ W + bias2)
//   block tile 128x128, BK=32, 4 waves each 64x64 via 2x2 mfma_f32_32x32x16_bf16
//   Register diet for __launch_bounds__(256,4): 64 AGPR acc + <=64 VGPR total
//   -> 4 blocks/CU, grid 1024 = exactly 4 rounds of 256 CUs (no ragged tail).
//   Staging uses scalar (SGPR) bases + one shared per-lane v-offset per array.
// ---------------------------------------------------------------------------
__global__ __launch_bounds__(256, 4) void unl_gemm_kernel(
    const float* __restrict__ X,
    const uint16_t* __restrict__ BtHi,
    const uint16_t* __restrict__ BtLo,
    const float* __restrict__ bias2,
    float* __restrict__ Out) {
  __shared__ __align__(16) uint8_t smem[32768];
  char* sA = (char*)smem;           // [128][32] fp32, 16B-swizzled (16KB)
  char* sBh = (char*)smem + 16384;  // [128][32] bf16 hi, swizzled (8KB)
  char* sBl = (char*)smem + 24576;  // [128][32] bf16 lo, swizzled (8KB)

  const int tid = threadIdx.x;
  const int lane = tid & 63;
  // wave index forced scalar so all staging bases become SGPR-resident
  const int wq = __builtin_amdgcn_readfirstlane(tid >> 6);
  const int wM = wq >> 1;
  const int wN = wq & 1;
  const int lane31 = lane & 31;
  const int kh = lane >> 5;  // k-half selector for MFMA operand layout

  const int bidx = blockIdx.x;
  const int m0 = (bidx & 63) * 128;  // 64 m-tiles
  const int n0 = (bidx >> 6) * 128;  // 16 n-tiles

  // ---- staging: uniform bases (SGPR) + shared per-lane byte offsets ----
  // A: 16 chunks of 1KB; chunk idx = wq*4+q covers rows idx*8..idx*8+7,
  //    lane -> row idx*8+(lane>>3), physical 16B block p=lane&7 holds
  //    logical k-block c = p ^ (row&7)  (row&7 == lane>>3 since idx*8%8==0)
  const int aC = (lane & 7) ^ (lane >> 3);
  const int aVoff = ((lane >> 3) * KK + aC * 4) * 4;  // bytes into A row-block
  const char* aBase = (const char*)(X + (size_t)(m0 + wq * 32) * KK) + aVoff;
  // B: 8 chunks of 1KB each for hi/lo; chunk idx = wq*2+q covers 16 rows,
  //    lane -> row idx*16+(lane>>2), p=lane&3, c = p ^ ((row>>1)&3)
  const int bC = (lane & 3) ^ ((lane >> 3) & 3);
  const int bVoff = ((lane >> 2) * KK + bC * 8) * 2;  // bytes into B row-block
  const char* bBaseH = (const char*)(BtHi + (size_t)(n0 + wq * 32) * KK) + bVoff;
  const char* bBaseL = (const char*)(BtLo + (size_t)(n0 + wq * 32) * KK) + bVoff;

  // ---- fragment read byte-offsets (swizzle-corrected) ----
  // A read for (mt,s): row = wM*64+mt*32+lane31, logical c = 4s+2kh (+h2),
  //   byte addr = row*128 + (c^(row&7))*16 ; second 16B half = addr ^ 16.
  int aOffB[2][2];
#pragma unroll
  for (int mt = 0; mt < 2; ++mt) {
    int row = wM * 64 + mt * 32 + lane31;
#pragma unroll
    for (int s = 0; s < 2; ++s)
      aOffB[mt][s] = row * 128 + (((4 * s + 2 * kh) ^ (row & 7)) * 16);
  }
  // B read for (nt,s): row = wN*64+nt*32+lane31, c = 2s+kh,
  //   byte addr = row*64 + (c^((row>>1)&3))*16
  int bOffB[2][2];
#pragma unroll
  for (int nt = 0; nt < 2; ++nt) {
    int row = wN * 64 + nt * 32 + lane31;
#pragma unroll
    for (int s = 0; s < 2; ++s)
      bOffB[nt][s] = row * 64 + (((2 * s + kh) ^ ((row >> 1) & 3)) * 16);
  }

  f32x16 acc[2][2];
#pragma unroll
  for (int mt = 0; mt < 2; ++mt)
#pragma unroll
    for (int nt = 0; nt < 2; ++nt)
#pragma unroll
      for (int r = 0; r < 16; ++r) acc[mt][nt][r] = 0.0f;

  for (int kt = 0; kt < KK; kt += 32) {
    __syncthreads();  // previous tile fully consumed
#pragma unroll
    for (int q = 0; q < 4; ++q)
      load_lds16(aBase + (size_t)kt * 4 + (size_t)q * (8 * KK * 4),
                 sA + (wq * 4 + q) * 1024);
#pragma unroll
    for (int q = 0; q < 2; ++q) {
      load_lds16(bBaseH + (size_t)kt * 2 + (size_t)q * (16 * KK * 2),
                 sBh + (wq * 2 + q) * 1024);
      load_lds16(bBaseL + (size_t)kt * 2 + (size_t)q * (16 * KK * 2),
                 sBl + (wq * 2 + q) * 1024);
    }
    __syncthreads();  // drains vmcnt: staging complete

#pragma unroll
    for (int s = 0; s < 2; ++s) {
      bf16x8 ah[2], al[2], bh[2], bl[2];
#pragma unroll
      for (int mt = 0; mt < 2; ++mt) {
        float4 v0 = *(const float4*)(sA + aOffB[mt][s]);
        float4 v1 = *(const float4*)(sA + (aOffB[mt][s] ^ 16));
        FragU uh, ul;
        split4(v0, uh.u[0], uh.u[1], ul.u[0], ul.u[1]);
        split4(v1, uh.u[2], uh.u[3], ul.u[2], ul.u[3]);
        ah[mt] = uh.v;
        al[mt] = ul.v;
      }
#pragma unroll
      for (int nt = 0; nt < 2; ++nt) {
        bh[nt] = *(const bf16x8*)(sBh + bOffB[nt][s]);
        bl[nt] = *(const bf16x8*)(sBl + bOffB[nt][s]);
      }
#pragma unroll
      for (int mt = 0; mt < 2; ++mt) {
#pragma unroll
        for (int nt = 0; nt < 2; ++nt) {
          acc[mt][nt] = __builtin_amdgcn_mfma_f32_32x32x16_bf16(ah[mt], bh[nt], acc[mt][nt], 0, 0, 0);
          acc[mt][nt] = __builtin_amdgcn_mfma_f32_32x32x16_bf16(ah[mt], bl[nt], acc[mt][nt], 0, 0, 0);
          acc[mt][nt] = __builtin_amdgcn_mfma_f32_32x32x16_bf16(al[mt], bh[nt], acc[mt][nt], 0, 0, 0);
        }
      }
    }
  }

  // ---- epilogue: out = tanh(acc + bias2) ----
  // C/D layout (verified m74/m101): col = lane&31, row = (r&3) + 8*(r>>2) + 4*kh
#pragma unroll
  for (int nt = 0; nt < 2; ++nt) {
    int col = n0 + wN * 64 + nt * 32 + lane31;
    float b2 = bias2[col];
#pragma unroll
    for (int mt = 0; mt < 2; ++mt) {
#pragma unroll
      for (int r = 0; r < 16; ++r) {
        int rowl = (r & 3) + 8 * (r >> 2) + 4 * kh;
        int grow = m0 + wM * 64 + mt * 32 + rowl;
        float z = acc[mt][nt][r] + b2;
        z = fminf(fmaxf(z, -12.0f), 12.0f);  // tanh saturated well before 12
        float t = __expf(2.0f * z);
        Out[(size_t)grow * NN + col] = (t - 1.0f) / (t + 1.0f);
      }
    }
  }
}

// ---------------------------------------------------------------------------
extern "C" void kernel_launch(void* const* d_in, const int* in_sizes, int n_in,
                              void* d_out, int out_size, void* d_ws, size_t ws_size,
                              hipStream_t stream) {
  const float* x = (const float*)d_in[0];   // (8192, 4096)
  const float* uw = (const float*)d_in[1];  // (9, 4096, 2048)
  const float* cw = (const float*)d_in[2];  // (4096, 2048)
  const float* cb = (const float*)d_in[3];  // (2048,)
  float* out = (float*)d_out;               // (8192, 2048)

  // workspace layout: BtHi (16MB) | BtLo (16MB) | bias2 (8KB)
  uint16_t* btHi = (uint16_t*)d_ws;
  uint16_t* btLo = btHi + (size_t)NN * KK;
  float* bias2 = (float*)(btLo + (size_t)NN * KK);

  prep_bt_kernel<<<dim3(KK / 64, NN / 64), 256, 0, stream>>>(cw, btHi, btLo);
  prep_bias_kernel<<<dim3(NN / 256), 256, 0, stream>>>(uw, cb, bias2);
  unl_gemm_kernel<<<dim3((MM / 128) * (NN / 128)), 256, 0, stream>>>(x, btHi, btLo, bias2, out);
}